// Round 1
// baseline (734.275 us; speedup 1.0000x reference)
//
#include <hip/hip_runtime.h>
#include <stdint.h>

// ---- problem constants ----
#define NB 2
#define NL 1024
#define ND 2048
#define NE 4096
#define NN 16
#define NR 128
#define NKC 4
#define NBL (NB*NL)          // 2048 rows
#define EPSV 1e-5f

typedef __attribute__((ext_vector_type(4))) float f32x4;
typedef __attribute__((ext_vector_type(8))) short short8;
typedef __attribute__((ext_vector_type(8))) unsigned short ushort8;

__device__ __forceinline__ unsigned short f2bf(float f) {
  union { float f; unsigned u; } v; v.f = f;
  unsigned r = v.u + 0x7FFFu + ((v.u >> 16) & 1u);   // RNE
  return (unsigned short)(r >> 16);
}

__device__ __forceinline__ void load_lds16(const void* g, void* l) {
  __builtin_amdgcn_global_load_lds((const __attribute__((address_space(1))) void*)g,
                                   (__attribute__((address_space(3))) void*)l,
                                   16, 0, 0);
}

// ---------------- RMSNorm: resid[row,0:2048] -> rn_bf16 ----------------
__global__ void rmsnorm_kernel(const float* __restrict__ resid,
                               const float* __restrict__ nw,
                               unsigned short* __restrict__ rn) {
  int row = blockIdx.x;
  int tid = threadIdx.x;                 // 256 threads, 8 f32 each
  const float* r = resid + (size_t)row * ND;
  f32x4 v0 = *(const f32x4*)(r + tid * 8);
  f32x4 v1 = *(const f32x4*)(r + tid * 8 + 4);
  float vals[8];
#pragma unroll
  for (int i = 0; i < 4; ++i) { vals[i] = v0[i]; vals[4 + i] = v1[i]; }
  float ss = 0.f;
#pragma unroll
  for (int i = 0; i < 8; ++i) ss += vals[i] * vals[i];
  for (int o = 32; o > 0; o >>= 1) ss += __shfl_down(ss, o);
  __shared__ float ps[4];
  if ((tid & 63) == 0) ps[tid >> 6] = ss;
  __syncthreads();
  float tot = ps[0] + ps[1] + ps[2] + ps[3];
  float scale = rsqrtf(tot / (float)ND + EPSV);
  ushort8 o8;
#pragma unroll
  for (int i = 0; i < 8; ++i) o8[i] = f2bf(vals[i] * scale * nw[tid * 8 + i]);
  *(ushort8*)(rn + (size_t)row * ND + tid * 8) = o8;
}

// ---------------- generic f32 -> bf16 cast (8 elems/thread) ----------------
__global__ void cast_bf16_kernel(const float* __restrict__ in,
                                 unsigned short* __restrict__ out, int n8) {
  int i = blockIdx.x * blockDim.x + threadIdx.x;
  if (i >= n8) return;
  f32x4 a = *(const f32x4*)(in + (size_t)i * 8);
  f32x4 b = *(const f32x4*)(in + (size_t)i * 8 + 4);
  ushort8 o;
#pragma unroll
  for (int j = 0; j < 4; ++j) { o[j] = f2bf(a[j]); o[4 + j] = f2bf(b[j]); }
  *(ushort8*)(out + (size_t)i * 8) = o;
}

// ---- build concatenated [256 x 4096] bf16 weight: rows 0-127 wd1, 128-143 wB, 144-159 wC, rest 0
__global__ void build_wcat_kernel(const float* __restrict__ wd1,
                                  const float* __restrict__ wB,
                                  const float* __restrict__ wC,
                                  unsigned short* __restrict__ out) {
  int i = blockIdx.x * blockDim.x + threadIdx.x;   // total 256*4096/8 = 131072
  if (i >= 256 * NE / 8) return;
  int col8 = i & (NE / 8 - 1);
  int row = i >> 9;
  const float* src = nullptr; int srow = 0;
  if (row < 128)      { src = wd1; srow = row; }
  else if (row < 144) { src = wB;  srow = row - 128; }
  else if (row < 160) { src = wC;  srow = row - 144; }
  ushort8 o;
  if (src) {
    f32x4 a = *(const f32x4*)(src + (size_t)srow * NE + col8 * 8);
    f32x4 b = *(const f32x4*)(src + (size_t)srow * NE + col8 * 8 + 4);
#pragma unroll
    for (int j = 0; j < 4; ++j) { o[j] = f2bf(a[j]); o[4 + j] = f2bf(b[j]); }
  } else {
#pragma unroll
    for (int j = 0; j < 8; ++j) o[j] = 0;
  }
  *(ushort8*)(out + (size_t)row * NE + col8 * 8) = o;
}

// ---------------- bf16 MFMA GEMM: C[M,N] = A[M,K] @ B[N,K]^T ----------------
// 128x128 tile, 256 threads (4 waves 2x2), BK=32, global_load_lds staging (m97 structure).
// MODE 0: plain f32 store (with split-K partials via blockIdx.z)
// MODE 1: softplus(acc + bias[n])
// MODE 2: acc + add[idx]  (residual)
template<int MODE>
__global__ __launch_bounds__(256)
void gemm_bt(const unsigned short* __restrict__ A,
             const unsigned short* __restrict__ B,
             float* __restrict__ C,
             int M, int N, int K, int ksteps_per_z,
             const float* __restrict__ bias,
             const float* __restrict__ add) {
  __shared__ unsigned short As[128 * 32];
  __shared__ unsigned short Bs[128 * 32];
  int tid = threadIdx.x;
  int w = tid >> 6, lane = tid & 63;
  int m0 = blockIdx.y * 128, n0 = blockIdx.x * 128;
  int kz0 = blockIdx.z * ksteps_per_z * 32;
  if (MODE == 0) C += (size_t)blockIdx.z * M * N;

  f32x4 zero = {0.f, 0.f, 0.f, 0.f};
  f32x4 acc[4][4];
#pragma unroll
  for (int i = 0; i < 4; ++i)
#pragma unroll
    for (int j = 0; j < 4; ++j) acc[i][j] = zero;

  int wm = w >> 1, wn = w & 1;
  int lr = lane & 15, kg = lane >> 4;

  // staging geometry: issue i (0,1): flat elem = (i*4+w)*512 + lane*8
  int fe0 = (w)*512 + lane * 8;
  int fe1 = (4 + w) * 512 + lane * 8;
  int r0 = fe0 >> 5, c0 = fe0 & 31;
  int r1 = fe1 >> 5, c1 = fe1 & 31;
  const unsigned short* Ag0 = A + (size_t)(m0 + r0) * K + c0;
  const unsigned short* Ag1 = A + (size_t)(m0 + r1) * K + c1;
  const unsigned short* Bg0 = B + (size_t)(n0 + r0) * K + c0;
  const unsigned short* Bg1 = B + (size_t)(n0 + r1) * K + c1;
  unsigned short* Al0 = As + (w) * 512;
  unsigned short* Al1 = As + (4 + w) * 512;
  unsigned short* Bl0 = Bs + (w) * 512;
  unsigned short* Bl1 = Bs + (4 + w) * 512;

  for (int ks = 0; ks < ksteps_per_z; ++ks) {
    int kk = kz0 + ks * 32;
    __syncthreads();
    load_lds16(Ag0 + kk, Al0);
    load_lds16(Ag1 + kk, Al1);
    load_lds16(Bg0 + kk, Bl0);
    load_lds16(Bg1 + kk, Bl1);
    asm volatile("s_waitcnt vmcnt(0)" ::: "memory");
    __syncthreads();
    short8 a[4], b[4];
#pragma unroll
    for (int i = 0; i < 4; ++i)
      a[i] = *(const short8*)&As[(wm * 64 + i * 16 + lr) * 32 + kg * 8];
#pragma unroll
    for (int j = 0; j < 4; ++j)
      b[j] = *(const short8*)&Bs[(wn * 64 + j * 16 + lr) * 32 + kg * 8];
#pragma unroll
    for (int i = 0; i < 4; ++i)
#pragma unroll
      for (int j = 0; j < 4; ++j)
        acc[i][j] = __builtin_amdgcn_mfma_f32_16x16x32_bf16(a[i], b[j], acc[i][j], 0, 0, 0);
  }

  // epilogue: C/D layout col=lane&15, row=(lane>>4)*4+reg  (verified m89/m91)
#pragma unroll
  for (int i = 0; i < 4; ++i) {
#pragma unroll
    for (int j = 0; j < 4; ++j) {
      int rbase = m0 + wm * 64 + i * 16 + kg * 4;
      int col = n0 + wn * 64 + j * 16 + lr;
#pragma unroll
      for (int r = 0; r < 4; ++r) {
        float v = acc[i][j][r];
        size_t idx = (size_t)(rbase + r) * N + col;
        if (MODE == 0) {
          C[idx] = v;
        } else if (MODE == 1) {
          float t = v + bias[col];
          C[idx] = (t > 20.f) ? t : log1pf(__expf(t));
        } else {
          C[idx] = v + add[idx];
        }
      }
    }
  }
}

// ---------------- depthwise causal conv (K=4) + SiLU ----------------
__global__ void conv_silu_kernel(const float* __restrict__ xin,
                                 const float* __restrict__ cw,
                                 const float* __restrict__ cb,
                                 float* __restrict__ x,
                                 unsigned short* __restrict__ xbf) {
  size_t idx = (size_t)blockIdx.x * blockDim.x + threadIdx.x;
  if (idx >= (size_t)NB * NL * NE) return;
  int e = (int)(idx & (NE - 1));
  int l = (int)((idx >> 12) & (NL - 1));
  float acc = cb[e];
#pragma unroll
  for (int k = 0; k < NKC; ++k) {
    int ls = l - 3 + k;
    if (ls >= 0) acc += xin[idx + (size_t)(k - 3) * NE] * cw[e * 4 + k];
  }
  float s = acc / (1.f + __expf(-acc));
  x[idx] = s;
  xbf[idx] = f2bf(s);
}

// ---------------- reduce split-K partials of the concat GEMM ----------------
// part[8][NBL][256] -> t_bf[NBL][128], Bm[NBL][16], Cm[NBL][16]
__global__ void reduce_tcat_kernel(const float* __restrict__ part,
                                   unsigned short* __restrict__ tbf,
                                   float* __restrict__ Bm,
                                   float* __restrict__ Cm) {
  int idx = blockIdx.x * blockDim.x + threadIdx.x;
  if (idx >= NBL * 160) return;
  int m = idx / 160, c = idx - m * 160;
  float s = 0.f;
#pragma unroll
  for (int z = 0; z < 8; ++z) s += part[(size_t)z * NBL * 256 + (size_t)m * 256 + c];
  if (c < 128) tbf[m * 128 + c] = f2bf(s);
  else if (c < 144) Bm[m * 16 + (c - 128)] = s;
  else Cm[m * 16 + (c - 144)] = s;
}

// ---------------- selective-scan + D-skip + gating, writes bf16 ----------------
// lane n = state index (16 lanes per (b,e)), 16 e's per block.
__global__ __launch_bounds__(256)
void scan_kernel(const float* __restrict__ delta,
                 const float* __restrict__ x,
                 const float* __restrict__ Bm,
                 const float* __restrict__ Cm,
                 const float* __restrict__ skip,
                 const float* __restrict__ A_log,
                 const float* __restrict__ W_D,
                 unsigned short* __restrict__ yg) {
  int tid = threadIdx.x;
  int n = tid & 15, el = tid >> 4;
  int e = blockIdx.x * 16 + el;
  int b = blockIdx.y;
  float Aen = -__expf(A_log[e * 16 + n]);
  float wd = W_D[e];
  float h = 0.f;
  size_t base = (size_t)b * NL * NE + e;
  size_t bc = (size_t)b * NL * 16 + n;
  float dc = delta[base], xc = x[base], Bc = Bm[bc], Cc = Cm[bc], sc = skip[base];
  for (int l = 0; l < NL; ++l) {
    float dn = 0.f, xn = 0.f, Bn = 0.f, Cn = 0.f, sn = 0.f;
    if (l + 1 < NL) {
      size_t i2 = base + (size_t)(l + 1) * NE;
      size_t b2 = bc + (size_t)(l + 1) * 16;
      dn = delta[i2]; xn = x[i2]; Bn = Bm[b2]; Cn = Cm[b2]; sn = skip[i2];
    }
    h = __expf(dc * Aen) * h + dc * xc * Bc;
    float p = h * Cc;
    p += __shfl_xor(p, 1, 16);
    p += __shfl_xor(p, 2, 16);
    p += __shfl_xor(p, 4, 16);
    p += __shfl_xor(p, 8, 16);
    if (n == 0) {
      float y = p + xc * wd;
      float g = sc / (1.f + __expf(-sc));
      yg[base + (size_t)l * NE] = f2bf(y * g);
    }
    dc = dn; xc = xn; Bc = Bn; Cc = Cn; sc = sn;
  }
}

// ---------------- host launcher ----------------
extern "C" void kernel_launch(void* const* d_in, const int* in_sizes, int n_in,
                              void* d_out, int out_size, void* d_ws, size_t ws_size,
                              hipStream_t stream) {
  const float* resid  = (const float*)d_in[0];
  const float* norm_w = (const float*)d_in[1];
  const float* skip_w = (const float*)d_in[2];
  const float* in_w   = (const float*)d_in[3];
  const float* conv_w = (const float*)d_in[4];
  const float* conv_b = (const float*)d_in[5];
  const float* wd1    = (const float*)d_in[6];
  const float* wd2    = (const float*)d_in[7];
  const float* wd2_b  = (const float*)d_in[8];
  const float* wB     = (const float*)d_in[9];
  const float* wC     = (const float*)d_in[10];
  const float* A_log  = (const float*)d_in[11];
  const float* W_D    = (const float*)d_in[12];
  const float* out_w  = (const float*)d_in[13];
  float* out = (float*)d_out;

  char* ws = (char*)d_ws;
  size_t off = 0;
  auto alloc = [&](size_t bytes) -> void* {
    void* p = ws + off;
    off += (bytes + 255) & ~(size_t)255;
    return p;
  };
  unsigned short* rn_bf    = (unsigned short*)alloc((size_t)NBL * ND * 2);
  unsigned short* wskip_bf = (unsigned short*)alloc((size_t)NE * ND * 2);
  unsigned short* win_bf   = (unsigned short*)alloc((size_t)NE * ND * 2);
  unsigned short* wout_bf  = (unsigned short*)alloc((size_t)ND * NE * 2);
  unsigned short* wd2_bf   = (unsigned short*)alloc((size_t)NE * NR * 2);
  unsigned short* wcat_bf  = (unsigned short*)alloc((size_t)256 * NE * 2);
  float* skip_f            = (float*)alloc((size_t)NBL * NE * 4);
  float* xin_f             = (float*)alloc((size_t)NBL * NE * 4);   // reused as delta
  float* x_f               = (float*)alloc((size_t)NBL * NE * 4);
  unsigned short* x_bf     = (unsigned short*)alloc((size_t)NBL * NE * 2);
  float* part_f            = (float*)alloc((size_t)8 * NBL * 256 * 4);
  unsigned short* t_bf     = (unsigned short*)alloc((size_t)NBL * NR * 2);
  float* Bm_f              = (float*)alloc((size_t)NBL * 16 * 4);
  float* Cm_f              = (float*)alloc((size_t)NBL * 16 * 4);
  unsigned short* yg_bf    = (unsigned short*)alloc((size_t)NBL * NE * 2);
  float* delta_f = xin_f;
  (void)ws_size; (void)in_sizes; (void)n_in; (void)out_size;

  // 1. RMSNorm -> rn bf16
  rmsnorm_kernel<<<dim3(NBL), dim3(256), 0, stream>>>(resid, norm_w, rn_bf);

  // 2. weight casts
  cast_bf16_kernel<<<dim3((NE * ND / 8 + 255) / 256), dim3(256), 0, stream>>>(skip_w, wskip_bf, NE * ND / 8);
  cast_bf16_kernel<<<dim3((NE * ND / 8 + 255) / 256), dim3(256), 0, stream>>>(in_w, win_bf, NE * ND / 8);
  cast_bf16_kernel<<<dim3((ND * NE / 8 + 255) / 256), dim3(256), 0, stream>>>(out_w, wout_bf, ND * NE / 8);
  cast_bf16_kernel<<<dim3((NE * NR / 8 + 255) / 256), dim3(256), 0, stream>>>(wd2, wd2_bf, NE * NR / 8);
  build_wcat_kernel<<<dim3(256 * NE / 8 / 256), dim3(256), 0, stream>>>(wd1, wB, wC, wcat_bf);

  // 3. skip = rn @ skip_w^T   [2048,4096] k=2048
  gemm_bt<0><<<dim3(NE / 128, NBL / 128, 1), dim3(256), 0, stream>>>(
      rn_bf, wskip_bf, skip_f, NBL, NE, ND, ND / 32, nullptr, nullptr);
  // 4. x_in = rn @ in_w^T
  gemm_bt<0><<<dim3(NE / 128, NBL / 128, 1), dim3(256), 0, stream>>>(
      rn_bf, win_bf, xin_f, NBL, NE, ND, ND / 32, nullptr, nullptr);

  // 5. conv + silu -> x (f32 + bf16)
  conv_silu_kernel<<<dim3((int)(((size_t)NB * NL * NE) / 256)), dim3(256), 0, stream>>>(
      xin_f, conv_w, conv_b, x_f, x_bf);

  // 6. tcat = x @ [wd1;wB;wC]^T  split-K=8 -> partials
  gemm_bt<0><<<dim3(256 / 128, NBL / 128, 8), dim3(256), 0, stream>>>(
      x_bf, wcat_bf, part_f, NBL, 256, NE, (NE / 32) / 8, nullptr, nullptr);
  // 7. reduce partials -> t_bf, Bm, Cm
  reduce_tcat_kernel<<<dim3((NBL * 160 + 255) / 256), dim3(256), 0, stream>>>(
      part_f, t_bf, Bm_f, Cm_f);

  // 8. delta = softplus(t @ wd2^T + wd2_b)   [2048,4096] k=128  (writes into xin_f)
  gemm_bt<1><<<dim3(NE / 128, NBL / 128, 1), dim3(256), 0, stream>>>(
      t_bf, wd2_bf, delta_f, NBL, NE, NR, NR / 32, wd2_b, nullptr);

  // 9. selective scan + D-skip + gating -> yg bf16
  scan_kernel<<<dim3(NE / 16, NB), dim3(256), 0, stream>>>(
      delta_f, x_f, Bm_f, Cm_f, skip_f, A_log, W_D, yg_bf);

  // 10. out = resid + yg @ out_w^T   [2048,2048] k=4096
  gemm_bt<2><<<dim3(ND / 128, NBL / 128, 1), dim3(256), 0, stream>>>(
      yg_bf, wout_bf, out, NBL, ND, NE, NE / 32, nullptr, resid);
}

// Round 3
// 479.164 us; speedup vs baseline: 1.5324x; 1.5324x over previous
//
#include <hip/hip_runtime.h>
#include <stdint.h>

// ---- problem constants ----
#define NB 2
#define NL 1024
#define ND 2048
#define NE 4096
#define NN 16
#define NR 128
#define NKC 4
#define NBL (NB*NL)          // 2048 rows
#define EPSV 1e-5f

typedef __attribute__((ext_vector_type(4))) float f32x4;
typedef __attribute__((ext_vector_type(8))) short short8;
typedef __attribute__((ext_vector_type(8))) unsigned short ushort8;
typedef __attribute__((ext_vector_type(4))) unsigned short ushort4_t;

__device__ __forceinline__ unsigned short f2bf(float f) {
  union { float f; unsigned u; } v; v.f = f;
  unsigned r = v.u + 0x7FFFu + ((v.u >> 16) & 1u);   // RNE
  return (unsigned short)(r >> 16);
}

__device__ __forceinline__ void load_lds16(const void* g, void* l) {
  __builtin_amdgcn_global_load_lds((const __attribute__((address_space(1))) void*)g,
                                   (__attribute__((address_space(3))) void*)l,
                                   16, 0, 0);
}

template<int CTRL>
__device__ __forceinline__ float dpp_mov(float v) {
  return __int_as_float(__builtin_amdgcn_update_dpp(
      0, __float_as_int(v), CTRL, 0xF, 0xF, true));
}

// ---------------- RMSNorm: resid[row,0:2048] -> rn_bf16 ----------------
__global__ void rmsnorm_kernel(const float* __restrict__ resid,
                               const float* __restrict__ nw,
                               unsigned short* __restrict__ rn) {
  int row = blockIdx.x;
  int tid = threadIdx.x;                 // 256 threads, 8 f32 each
  const float* r = resid + (size_t)row * ND;
  f32x4 v0 = *(const f32x4*)(r + tid * 8);
  f32x4 v1 = *(const f32x4*)(r + tid * 8 + 4);
  float vals[8];
#pragma unroll
  for (int i = 0; i < 4; ++i) { vals[i] = v0[i]; vals[4 + i] = v1[i]; }
  float ss = 0.f;
#pragma unroll
  for (int i = 0; i < 8; ++i) ss += vals[i] * vals[i];
  for (int o = 32; o > 0; o >>= 1) ss += __shfl_down(ss, o);
  __shared__ float ps[4];
  if ((tid & 63) == 0) ps[tid >> 6] = ss;
  __syncthreads();
  float tot = ps[0] + ps[1] + ps[2] + ps[3];
  float scale = rsqrtf(tot / (float)ND + EPSV);
  ushort8 o8;
#pragma unroll
  for (int i = 0; i < 8; ++i) o8[i] = f2bf(vals[i] * scale * nw[tid * 8 + i]);
  *(ushort8*)(rn + (size_t)row * ND + tid * 8) = o8;
}

// ---------------- generic f32 -> bf16 cast (8 elems/thread) ----------------
__global__ void cast_bf16_kernel(const float* __restrict__ in,
                                 unsigned short* __restrict__ out, int n8) {
  int i = blockIdx.x * blockDim.x + threadIdx.x;
  if (i >= n8) return;
  f32x4 a = *(const f32x4*)(in + (size_t)i * 8);
  f32x4 b = *(const f32x4*)(in + (size_t)i * 8 + 4);
  ushort8 o;
#pragma unroll
  for (int j = 0; j < 4; ++j) { o[j] = f2bf(a[j]); o[4 + j] = f2bf(b[j]); }
  *(ushort8*)(out + (size_t)i * 8) = o;
}

// ---- build concatenated [256 x 4096] bf16 weight: rows 0-127 wd1, 128-143 wB, 144-159 wC, rest 0
__global__ void build_wcat_kernel(const float* __restrict__ wd1,
                                  const float* __restrict__ wB,
                                  const float* __restrict__ wC,
                                  unsigned short* __restrict__ out) {
  int i = blockIdx.x * blockDim.x + threadIdx.x;   // total 256*4096/8 = 131072
  if (i >= 256 * NE / 8) return;
  int col8 = i & (NE / 8 - 1);
  int row = i >> 9;
  const float* src = nullptr; int srow = 0;
  if (row < 128)      { src = wd1; srow = row; }
  else if (row < 144) { src = wB;  srow = row - 128; }
  else if (row < 160) { src = wC;  srow = row - 144; }
  ushort8 o;
  if (src) {
    f32x4 a = *(const f32x4*)(src + (size_t)srow * NE + col8 * 8);
    f32x4 b = *(const f32x4*)(src + (size_t)srow * NE + col8 * 8 + 4);
#pragma unroll
    for (int j = 0; j < 4; ++j) { o[j] = f2bf(a[j]); o[4 + j] = f2bf(b[j]); }
  } else {
#pragma unroll
    for (int j = 0; j < 8; ++j) o[j] = 0;
  }
  *(ushort8*)(out + (size_t)row * NE + col8 * 8) = o;
}

// ---------------- bf16 MFMA GEMM: C[M,N] = A[M,K] @ B[N,K]^T ----------------
// 128x128 tile, 256 threads (4 waves 2x2), BK=32, global_load_lds staging (m97 structure).
// MODE 0: plain f32 store (with split-K partials via blockIdx.z)
// MODE 1: softplus(acc + bias[n])
// MODE 2: acc + add[idx]  (residual)
template<int MODE>
__global__ __launch_bounds__(256)
void gemm_bt(const unsigned short* __restrict__ A,
             const unsigned short* __restrict__ B,
             float* __restrict__ C,
             int M, int N, int K, int ksteps_per_z,
             const float* __restrict__ bias,
             const float* __restrict__ add) {
  __shared__ unsigned short As[128 * 32];
  __shared__ unsigned short Bs[128 * 32];
  int tid = threadIdx.x;
  int w = tid >> 6, lane = tid & 63;
  int m0 = blockIdx.y * 128, n0 = blockIdx.x * 128;
  int kz0 = blockIdx.z * ksteps_per_z * 32;
  if (MODE == 0) C += (size_t)blockIdx.z * M * N;

  f32x4 zero = {0.f, 0.f, 0.f, 0.f};
  f32x4 acc[4][4];
#pragma unroll
  for (int i = 0; i < 4; ++i)
#pragma unroll
    for (int j = 0; j < 4; ++j) acc[i][j] = zero;

  int wm = w >> 1, wn = w & 1;
  int lr = lane & 15, kg = lane >> 4;

  // staging geometry: issue i (0,1): flat elem = (i*4+w)*512 + lane*8
  int fe0 = (w)*512 + lane * 8;
  int fe1 = (4 + w) * 512 + lane * 8;
  int r0 = fe0 >> 5, c0 = fe0 & 31;
  int r1 = fe1 >> 5, c1 = fe1 & 31;
  const unsigned short* Ag0 = A + (size_t)(m0 + r0) * K + c0;
  const unsigned short* Ag1 = A + (size_t)(m0 + r1) * K + c1;
  const unsigned short* Bg0 = B + (size_t)(n0 + r0) * K + c0;
  const unsigned short* Bg1 = B + (size_t)(n0 + r1) * K + c1;
  unsigned short* Al0 = As + (w) * 512;
  unsigned short* Al1 = As + (4 + w) * 512;
  unsigned short* Bl0 = Bs + (w) * 512;
  unsigned short* Bl1 = Bs + (4 + w) * 512;

  for (int ks = 0; ks < ksteps_per_z; ++ks) {
    int kk = kz0 + ks * 32;
    __syncthreads();
    load_lds16(Ag0 + kk, Al0);
    load_lds16(Ag1 + kk, Al1);
    load_lds16(Bg0 + kk, Bl0);
    load_lds16(Bg1 + kk, Bl1);
    asm volatile("s_waitcnt vmcnt(0)" ::: "memory");
    __syncthreads();
    short8 a[4], b[4];
#pragma unroll
    for (int i = 0; i < 4; ++i)
      a[i] = *(const short8*)&As[(wm * 64 + i * 16 + lr) * 32 + kg * 8];
#pragma unroll
    for (int j = 0; j < 4; ++j)
      b[j] = *(const short8*)&Bs[(wn * 64 + j * 16 + lr) * 32 + kg * 8];
#pragma unroll
    for (int i = 0; i < 4; ++i)
#pragma unroll
      for (int j = 0; j < 4; ++j)
        acc[i][j] = __builtin_amdgcn_mfma_f32_16x16x32_bf16(a[i], b[j], acc[i][j], 0, 0, 0);
  }

  // epilogue: C/D layout col=lane&15, row=(lane>>4)*4+reg  (verified m89/m91)
#pragma unroll
  for (int i = 0; i < 4; ++i) {
#pragma unroll
    for (int j = 0; j < 4; ++j) {
      int rbase = m0 + wm * 64 + i * 16 + kg * 4;
      int col = n0 + wn * 64 + j * 16 + lr;
#pragma unroll
      for (int r = 0; r < 4; ++r) {
        float v = acc[i][j][r];
        size_t idx = (size_t)(rbase + r) * N + col;
        if (MODE == 0) {
          C[idx] = v;
        } else if (MODE == 1) {
          float t = v + bias[col];
          C[idx] = (t > 20.f) ? t : log1pf(__expf(t));
        } else {
          C[idx] = v + add[idx];
        }
      }
    }
  }
}

// ---------------- depthwise causal conv (K=4) + SiLU ----------------
__global__ void conv_silu_kernel(const float* __restrict__ xin,
                                 const float* __restrict__ cw,
                                 const float* __restrict__ cb,
                                 float* __restrict__ x,
                                 unsigned short* __restrict__ xbf) {
  size_t idx = (size_t)blockIdx.x * blockDim.x + threadIdx.x;
  if (idx >= (size_t)NB * NL * NE) return;
  int e = (int)(idx & (NE - 1));
  int l = (int)((idx >> 12) & (NL - 1));
  float acc = cb[e];
#pragma unroll
  for (int k = 0; k < NKC; ++k) {
    int ls = l - 3 + k;
    if (ls >= 0) acc += xin[idx + (size_t)(k - 3) * NE] * cw[e * 4 + k];
  }
  float s = acc / (1.f + __expf(-acc));
  x[idx] = s;
  xbf[idx] = f2bf(s);
}

// ---------------- reduce split-K partials of the concat GEMM ----------------
// part[8][NBL][256] -> t_bf[NBL][128], Bm[NBL][16], Cm[NBL][16]
__global__ void reduce_tcat_kernel(const float* __restrict__ part,
                                   unsigned short* __restrict__ tbf,
                                   float* __restrict__ Bm,
                                   float* __restrict__ Cm) {
  int idx = blockIdx.x * blockDim.x + threadIdx.x;
  if (idx >= NBL * 160) return;
  int m = idx / 160, c = idx - m * 160;
  float s = 0.f;
#pragma unroll
  for (int z = 0; z < 8; ++z) s += part[(size_t)z * NBL * 256 + (size_t)m * 256 + c];
  if (c < 128) tbf[m * 128 + c] = f2bf(s);
  else if (c < 144) Bm[m * 16 + (c - 128)] = s;
  else Cm[m * 16 + (c - 144)] = s;
}

// ---------------- selective-scan + D-skip + gating (LDS chunked, DPP reduce) ----
// block = 256 threads = 16 e's (one b); lane n = state index (16 lanes per e).
// T=64-step chunks double-buffered in LDS via global_load_lds (counted vmcnt).
#define SCAN_T 64
__global__ __launch_bounds__(256)
void scan_kernel(const float* __restrict__ delta,
                 const float* __restrict__ x,
                 const float* __restrict__ Bm,
                 const float* __restrict__ Cm,
                 const float* __restrict__ skip,
                 const float* __restrict__ A_log,
                 const float* __restrict__ W_D,
                 unsigned short* __restrict__ yg) {
  __shared__ float dl[2][SCAN_T][16];
  __shared__ float xl[2][SCAN_T][16];
  __shared__ float sl[2][SCAN_T][16];
  __shared__ float Bl[2][SCAN_T][16];
  __shared__ float Cl[2][SCAN_T][16];
  __shared__ float yl[SCAN_T][16];
  int tid = threadIdx.x;
  int n = tid & 15, el = tid >> 4;
  int w = tid >> 6, lane = tid & 63;
  int e0 = blockIdx.x * 16;
  int b = blockIdx.y;
  int e = e0 + el;
  float Aen = -__expf(A_log[e * 16 + n]);
  float wd = W_D[e];
  float h = 0.f;

  const float* gd = delta + (size_t)b * NL * NE + e0;
  const float* gx = x + (size_t)b * NL * NE + e0;
  const float* gs = skip + (size_t)b * NL * NE + e0;
  const float* gB = Bm + (size_t)b * NL * 16;
  const float* gC = Cm + (size_t)b * NL * 16;

  // staging geometry: wave w stages t-rows [w*16, w*16+16); lane covers
  // row w*16+(lane>>2), float-col (lane&3)*4  (16B per lane, HW adds lane*16 to LDS base)
  int srow = w * 16 + (lane >> 2);
  int scol = (lane & 3) * 4;

  auto stage = [&](int buf, int c) {
    int l0 = c * SCAN_T;
    load_lds16(gd + (size_t)(l0 + srow) * NE + scol, &dl[buf][w * 16][0]);
    load_lds16(gx + (size_t)(l0 + srow) * NE + scol, &xl[buf][w * 16][0]);
    load_lds16(gs + (size_t)(l0 + srow) * NE + scol, &sl[buf][w * 16][0]);
    load_lds16(gB + (size_t)l0 * 16 + w * 256 + lane * 4, &Bl[buf][w * 16][0]);
    load_lds16(gC + (size_t)l0 * 16 + w * 256 + lane * 4, &Cl[buf][w * 16][0]);
  };

  stage(0, 0);
  const int nch = NL / SCAN_T;  // 16
  for (int c = 0; c < nch; ++c) {
    int cur = c & 1;
    if (c + 1 < nch) {
      stage(cur ^ 1, c + 1);
      asm volatile("s_waitcnt vmcnt(5)" ::: "memory");  // chunk c done, c+1 in flight
    } else {
      asm volatile("s_waitcnt vmcnt(0)" ::: "memory");
    }
    __syncthreads();
    int l0 = c * SCAN_T;
#pragma unroll 4
    for (int t = 0; t < SCAN_T; ++t) {
      float dc = dl[cur][t][el];     // broadcast within e-group
      float xc = xl[cur][t][el];
      float Bc = Bl[cur][t][n];
      float Cc = Cl[cur][t][n];
      h = __expf(dc * Aen) * h + (dc * xc) * Bc;
      float p = h * Cc;
      // 16-lane sum via DPP tree (full-rate VALU, no LDS pipe)
      p += dpp_mov<0xB1>(p);    // quad_perm [1,0,3,2]  = xor1
      p += dpp_mov<0x4E>(p);    // quad_perm [2,3,0,1]  = xor2
      p += dpp_mov<0x141>(p);   // row_half_mirror      (combine quads in 8)
      p += dpp_mov<0x140>(p);   // row_mirror           (combine 8s in 16)
      if (n == 0) yl[t][el] = p + xc * wd;
    }
    __syncthreads();
    // write phase: gate with silu(skip), coalesced bf16 store (4 e's/thread)
    {
      int t = tid >> 2, part = tid & 3;
      f32x4 yv = *(const f32x4*)&yl[t][part * 4];
      f32x4 sv = *(const f32x4*)&sl[cur][t][part * 4];
      ushort4_t o;
#pragma unroll
      for (int j = 0; j < 4; ++j) {
        float g = sv[j] / (1.f + __expf(-sv[j]));
        o[j] = f2bf(yv[j] * g);
      }
      *(ushort4_t*)(yg + (size_t)(b * NL + l0 + t) * NE + e0 + part * 4) = o;
    }
    __syncthreads();  // protect sl[cur]/yl from next chunk's stage/compute
  }
}

// ---------------- host launcher ----------------
extern "C" void kernel_launch(void* const* d_in, const int* in_sizes, int n_in,
                              void* d_out, int out_size, void* d_ws, size_t ws_size,
                              hipStream_t stream) {
  const float* resid  = (const float*)d_in[0];
  const float* norm_w = (const float*)d_in[1];
  const float* skip_w = (const float*)d_in[2];
  const float* in_w   = (const float*)d_in[3];
  const float* conv_w = (const float*)d_in[4];
  const float* conv_b = (const float*)d_in[5];
  const float* wd1    = (const float*)d_in[6];
  const float* wd2    = (const float*)d_in[7];
  const float* wd2_b  = (const float*)d_in[8];
  const float* wB     = (const float*)d_in[9];
  const float* wC     = (const float*)d_in[10];
  const float* A_log  = (const float*)d_in[11];
  const float* W_D    = (const float*)d_in[12];
  const float* out_w  = (const float*)d_in[13];
  float* out = (float*)d_out;

  char* ws = (char*)d_ws;
  size_t off = 0;
  auto alloc = [&](size_t bytes) -> void* {
    void* p = ws + off;
    off += (bytes + 255) & ~(size_t)255;
    return p;
  };
  unsigned short* rn_bf    = (unsigned short*)alloc((size_t)NBL * ND * 2);
  unsigned short* wskip_bf = (unsigned short*)alloc((size_t)NE * ND * 2);
  unsigned short* win_bf   = (unsigned short*)alloc((size_t)NE * ND * 2);
  unsigned short* wout_bf  = (unsigned short*)alloc((size_t)ND * NE * 2);
  unsigned short* wd2_bf   = (unsigned short*)alloc((size_t)NE * NR * 2);
  unsigned short* wcat_bf  = (unsigned short*)alloc((size_t)256 * NE * 2);
  float* skip_f            = (float*)alloc((size_t)NBL * NE * 4);
  float* xin_f             = (float*)alloc((size_t)NBL * NE * 4);   // reused as delta
  float* x_f               = (float*)alloc((size_t)NBL * NE * 4);
  unsigned short* x_bf     = (unsigned short*)alloc((size_t)NBL * NE * 2);
  float* part_f            = (float*)alloc((size_t)8 * NBL * 256 * 4);
  unsigned short* t_bf     = (unsigned short*)alloc((size_t)NBL * NR * 2);
  float* Bm_f              = (float*)alloc((size_t)NBL * 16 * 4);
  float* Cm_f              = (float*)alloc((size_t)NBL * 16 * 4);
  unsigned short* yg_bf    = (unsigned short*)alloc((size_t)NBL * NE * 2);
  float* delta_f = xin_f;
  (void)ws_size; (void)in_sizes; (void)n_in; (void)out_size;

  // 1. RMSNorm -> rn bf16
  rmsnorm_kernel<<<dim3(NBL), dim3(256), 0, stream>>>(resid, norm_w, rn_bf);

  // 2. weight casts
  cast_bf16_kernel<<<dim3((NE * ND / 8 + 255) / 256), dim3(256), 0, stream>>>(skip_w, wskip_bf, NE * ND / 8);
  cast_bf16_kernel<<<dim3((NE * ND / 8 + 255) / 256), dim3(256), 0, stream>>>(in_w, win_bf, NE * ND / 8);
  cast_bf16_kernel<<<dim3((ND * NE / 8 + 255) / 256), dim3(256), 0, stream>>>(out_w, wout_bf, ND * NE / 8);
  cast_bf16_kernel<<<dim3((NE * NR / 8 + 255) / 256), dim3(256), 0, stream>>>(wd2, wd2_bf, NE * NR / 8);
  build_wcat_kernel<<<dim3(256 * NE / 8 / 256), dim3(256), 0, stream>>>(wd1, wB, wC, wcat_bf);

  // 3. skip = rn @ skip_w^T   [2048,4096] k=2048
  gemm_bt<0><<<dim3(NE / 128, NBL / 128, 1), dim3(256), 0, stream>>>(
      rn_bf, wskip_bf, skip_f, NBL, NE, ND, ND / 32, nullptr, nullptr);
  // 4. x_in = rn @ in_w^T
  gemm_bt<0><<<dim3(NE / 128, NBL / 128, 1), dim3(256), 0, stream>>>(
      rn_bf, win_bf, xin_f, NBL, NE, ND, ND / 32, nullptr, nullptr);

  // 5. conv + silu -> x (f32 + bf16)
  conv_silu_kernel<<<dim3((int)(((size_t)NB * NL * NE) / 256)), dim3(256), 0, stream>>>(
      xin_f, conv_w, conv_b, x_f, x_bf);

  // 6. tcat = x @ [wd1;wB;wC]^T  split-K=8 -> partials
  gemm_bt<0><<<dim3(256 / 128, NBL / 128, 8), dim3(256), 0, stream>>>(
      x_bf, wcat_bf, part_f, NBL, 256, NE, (NE / 32) / 8, nullptr, nullptr);
  // 7. reduce partials -> t_bf, Bm, Cm
  reduce_tcat_kernel<<<dim3((NBL * 160 + 255) / 256), dim3(256), 0, stream>>>(
      part_f, t_bf, Bm_f, Cm_f);

  // 8. delta = softplus(t @ wd2^T + wd2_b)   [2048,4096] k=128  (writes into xin_f)
  gemm_bt<1><<<dim3(NE / 128, NBL / 128, 1), dim3(256), 0, stream>>>(
      t_bf, wd2_bf, delta_f, NBL, NE, NR, NR / 32, wd2_b, nullptr);

  // 9. selective scan + D-skip + gating -> yg bf16
  scan_kernel<<<dim3(NE / 16, NB), dim3(256), 0, stream>>>(
      delta_f, x_f, Bm_f, Cm_f, skip_f, A_log, W_D, yg_bf);

  // 10. out = resid + yg @ out_w^T   [2048,2048] k=4096
  gemm_bt<2><<<dim3(ND / 128, NBL / 128, 1), dim3(256), 0, stream>>>(
      yg_bf, wout_bf, out, NBL, ND, NE, NE / 32, nullptr, resid);
}

// Round 5
// 458.130 us; speedup vs baseline: 1.6028x; 1.0459x over previous
//
#include <hip/hip_runtime.h>
#include <stdint.h>

// ---- problem constants ----
#define NB 2
#define NL 1024
#define ND 2048
#define NE 4096
#define NN 16
#define NR 128
#define NKC 4
#define NBL (NB*NL)          // 2048 rows
#define EPSV 1e-5f

typedef __attribute__((ext_vector_type(4))) float f32x4;
typedef __attribute__((ext_vector_type(8))) short short8;
typedef __attribute__((ext_vector_type(8))) unsigned short ushort8;
typedef __attribute__((ext_vector_type(4))) unsigned short ushort4_t;

__device__ __forceinline__ unsigned short f2bf(float f) {
  union { float f; unsigned u; } v; v.f = f;
  unsigned r = v.u + 0x7FFFu + ((v.u >> 16) & 1u);   // RNE
  return (unsigned short)(r >> 16);
}

__device__ __forceinline__ float bf2f(unsigned short u) {
  union { unsigned u; float f; } v; v.u = (unsigned)u << 16; return v.f;
}

__device__ __forceinline__ void load_lds16(const void* g, void* l) {
  __builtin_amdgcn_global_load_lds((const __attribute__((address_space(1))) void*)g,
                                   (__attribute__((address_space(3))) void*)l,
                                   16, 0, 0);
}

template<int CTRL>
__device__ __forceinline__ float dpp_mov(float v) {
  return __int_as_float(__builtin_amdgcn_update_dpp(
      0, __float_as_int(v), CTRL, 0xF, 0xF, true));
}

// ---------------- RMSNorm: resid[row,0:2048] -> rn_bf16 ----------------
__global__ void rmsnorm_kernel(const float* __restrict__ resid,
                               const float* __restrict__ nw,
                               unsigned short* __restrict__ rn) {
  int row = blockIdx.x;
  int tid = threadIdx.x;                 // 256 threads, 8 f32 each
  const float* r = resid + (size_t)row * ND;
  f32x4 v0 = *(const f32x4*)(r + tid * 8);
  f32x4 v1 = *(const f32x4*)(r + tid * 8 + 4);
  float vals[8];
#pragma unroll
  for (int i = 0; i < 4; ++i) { vals[i] = v0[i]; vals[4 + i] = v1[i]; }
  float ss = 0.f;
#pragma unroll
  for (int i = 0; i < 8; ++i) ss += vals[i] * vals[i];
  for (int o = 32; o > 0; o >>= 1) ss += __shfl_down(ss, o);
  __shared__ float ps[4];
  if ((tid & 63) == 0) ps[tid >> 6] = ss;
  __syncthreads();
  float tot = ps[0] + ps[1] + ps[2] + ps[3];
  float scale = rsqrtf(tot / (float)ND + EPSV);
  ushort8 o8;
#pragma unroll
  for (int i = 0; i < 8; ++i) o8[i] = f2bf(vals[i] * scale * nw[tid * 8 + i]);
  *(ushort8*)(rn + (size_t)row * ND + tid * 8) = o8;
}

// ---------------- generic f32 -> bf16 cast (8 elems/thread) ----------------
__global__ void cast_bf16_kernel(const float* __restrict__ in,
                                 unsigned short* __restrict__ out, int n8) {
  int i = blockIdx.x * blockDim.x + threadIdx.x;
  if (i >= n8) return;
  f32x4 a = *(const f32x4*)(in + (size_t)i * 8);
  f32x4 b = *(const f32x4*)(in + (size_t)i * 8 + 4);
  ushort8 o;
#pragma unroll
  for (int j = 0; j < 4; ++j) { o[j] = f2bf(a[j]); o[4 + j] = f2bf(b[j]); }
  *(ushort8*)(out + (size_t)i * 8) = o;
}

// ---- build concatenated [256 x 4096] bf16 weight: rows 0-127 wd1, 128-143 wB, 144-159 wC, rest 0
__global__ void build_wcat_kernel(const float* __restrict__ wd1,
                                  const float* __restrict__ wB,
                                  const float* __restrict__ wC,
                                  unsigned short* __restrict__ out) {
  int i = blockIdx.x * blockDim.x + threadIdx.x;   // total 256*4096/8 = 131072
  if (i >= 256 * NE / 8) return;
  int col8 = i & (NE / 8 - 1);
  int row = i >> 9;
  const float* src = nullptr; int srow = 0;
  if (row < 128)      { src = wd1; srow = row; }
  else if (row < 144) { src = wB;  srow = row - 128; }
  else if (row < 160) { src = wC;  srow = row - 144; }
  ushort8 o;
  if (src) {
    f32x4 a = *(const f32x4*)(src + (size_t)srow * NE + col8 * 8);
    f32x4 b = *(const f32x4*)(src + (size_t)srow * NE + col8 * 8 + 4);
#pragma unroll
    for (int j = 0; j < 4; ++j) { o[j] = f2bf(a[j]); o[4 + j] = f2bf(b[j]); }
  } else {
#pragma unroll
    for (int j = 0; j < 8; ++j) o[j] = 0;
  }
  *(ushort8*)(out + (size_t)row * NE + col8 * 8) = o;
}

// ---------------- bf16 MFMA GEMM: C[M,N] = A[M,K] @ B[N,K]^T ----------------
// 128x128 tile, 256 threads (4 waves 2x2), BK=32, global_load_lds staging (m97 structure).
// MODE 0: plain f32 store (with split-K partials via blockIdx.z)
// MODE 1: softplus(acc + bias[n]) -> bf16 store
// MODE 2: acc + add[idx]  (residual)
// MODE 3: col<4096 -> silu(acc) (gate prep); else raw acc  (fused skip+in proj)
template<int MODE>
__global__ __launch_bounds__(256)
void gemm_bt(const unsigned short* __restrict__ A,
             const unsigned short* __restrict__ B,
             float* __restrict__ C,
             int M, int N, int K, int ksteps_per_z,
             const float* __restrict__ bias,
             const float* __restrict__ add) {
  __shared__ unsigned short As[128 * 32];
  __shared__ unsigned short Bs[128 * 32];
  int tid = threadIdx.x;
  int w = tid >> 6, lane = tid & 63;
  int m0 = blockIdx.y * 128, n0 = blockIdx.x * 128;
  int kz0 = blockIdx.z * ksteps_per_z * 32;
  if (MODE == 0) C += (size_t)blockIdx.z * M * N;

  f32x4 zero = {0.f, 0.f, 0.f, 0.f};
  f32x4 acc[4][4];
#pragma unroll
  for (int i = 0; i < 4; ++i)
#pragma unroll
    for (int j = 0; j < 4; ++j) acc[i][j] = zero;

  int wm = w >> 1, wn = w & 1;
  int lr = lane & 15, kg = lane >> 4;

  // staging geometry: issue i (0,1): flat elem = (i*4+w)*512 + lane*8
  int fe0 = (w)*512 + lane * 8;
  int fe1 = (4 + w) * 512 + lane * 8;
  int r0 = fe0 >> 5, c0 = fe0 & 31;
  int r1 = fe1 >> 5, c1 = fe1 & 31;
  const unsigned short* Ag0 = A + (size_t)(m0 + r0) * K + c0;
  const unsigned short* Ag1 = A + (size_t)(m0 + r1) * K + c1;
  const unsigned short* Bg0 = B + (size_t)(n0 + r0) * K + c0;
  const unsigned short* Bg1 = B + (size_t)(n0 + r1) * K + c1;
  unsigned short* Al0 = As + (w) * 512;
  unsigned short* Al1 = As + (4 + w) * 512;
  unsigned short* Bl0 = Bs + (w) * 512;
  unsigned short* Bl1 = Bs + (4 + w) * 512;

  for (int ks = 0; ks < ksteps_per_z; ++ks) {
    int kk = kz0 + ks * 32;
    __syncthreads();
    load_lds16(Ag0 + kk, Al0);
    load_lds16(Ag1 + kk, Al1);
    load_lds16(Bg0 + kk, Bl0);
    load_lds16(Bg1 + kk, Bl1);
    asm volatile("s_waitcnt vmcnt(0)" ::: "memory");
    __syncthreads();
    short8 a[4], b[4];
#pragma unroll
    for (int i = 0; i < 4; ++i)
      a[i] = *(const short8*)&As[(wm * 64 + i * 16 + lr) * 32 + kg * 8];
#pragma unroll
    for (int j = 0; j < 4; ++j)
      b[j] = *(const short8*)&Bs[(wn * 64 + j * 16 + lr) * 32 + kg * 8];
#pragma unroll
    for (int i = 0; i < 4; ++i)
#pragma unroll
      for (int j = 0; j < 4; ++j)
        acc[i][j] = __builtin_amdgcn_mfma_f32_16x16x32_bf16(a[i], b[j], acc[i][j], 0, 0, 0);
  }

  // epilogue: C/D layout col=lane&15, row=(lane>>4)*4+reg  (verified m89/m91)
#pragma unroll
  for (int i = 0; i < 4; ++i) {
#pragma unroll
    for (int j = 0; j < 4; ++j) {
      int rbase = m0 + wm * 64 + i * 16 + kg * 4;
      int col = n0 + wn * 64 + j * 16 + lr;
#pragma unroll
      for (int r = 0; r < 4; ++r) {
        float v = acc[i][j][r];
        size_t idx = (size_t)(rbase + r) * N + col;
        if (MODE == 0) {
          C[idx] = v;
        } else if (MODE == 1) {
          float t = v + bias[col];
          ((unsigned short*)C)[idx] = f2bf((t > 20.f) ? t : log1pf(__expf(t)));
        } else if (MODE == 2) {
          C[idx] = v + add[idx];
        } else {  // MODE 3: gate-prep silu for skip half, raw for x_in half
          if (n0 < 4096) C[idx] = v / (1.f + __expf(-v));
          else           C[idx] = v;
        }
      }
    }
  }
}

// ---------------- depthwise causal conv (K=4) + SiLU -> bf16 only ----------------
// xin lives in cat_f[row][4096 + e] (row stride 8192)
__global__ void conv_silu_kernel(const float* __restrict__ cat,
                                 const float* __restrict__ cw,
                                 const float* __restrict__ cb,
                                 unsigned short* __restrict__ xbf) {
  size_t idx = (size_t)blockIdx.x * blockDim.x + threadIdx.x;
  if (idx >= (size_t)NB * NL * NE) return;
  int e = (int)(idx & (NE - 1));
  int r = (int)(idx >> 12);            // b*NL + l
  int l = r & (NL - 1);
  float acc = cb[e];
#pragma unroll
  for (int k = 0; k < NKC; ++k) {
    int ls = l - 3 + k;
    if (ls >= 0) acc += cat[(size_t)(r - 3 + k) * 8192 + 4096 + e] * cw[e * 4 + k];
  }
  float s = acc / (1.f + __expf(-acc));
  xbf[idx] = f2bf(s);
}

// ---------------- reduce split-K partials of the concat GEMM ----------------
// part[8][NBL][256] -> t_bf[NBL][128], bc[NBL][32] (B in [0:16), C in [16:32))
__global__ void reduce_tcat_kernel(const float* __restrict__ part,
                                   unsigned short* __restrict__ tbf,
                                   float* __restrict__ bc) {
  int idx = blockIdx.x * blockDim.x + threadIdx.x;
  if (idx >= NBL * 160) return;
  int m = idx / 160, c = idx - m * 160;
  float s = 0.f;
#pragma unroll
  for (int z = 0; z < 8; ++z) s += part[(size_t)z * NBL * 256 + (size_t)m * 256 + c];
  if (c < 128) tbf[m * 128 + c] = f2bf(s);
  else if (c < 144) bc[m * 32 + (c - 128)] = s;
  else bc[m * 32 + 16 + (c - 144)] = s;
}

// ---------------- selective-scan + D-skip + gating (LDS chunked, DPP reduce) ----
// block = 256 threads = 16 e's (one b); lane n = state index (16 lanes per e).
// bf16 delta/x interleaved-staged; BC interleaved [m][32]; g pre-silu'd (f32).
#define SCAN_T 64
__global__ __launch_bounds__(256)
void scan_kernel(const unsigned short* __restrict__ delta_bf,
                 const unsigned short* __restrict__ x_bf,
                 const float* __restrict__ bc,
                 const float* __restrict__ gcat,    // g at cat_f[row][0:4096)
                 const float* __restrict__ A_log,
                 const float* __restrict__ W_D,
                 unsigned short* __restrict__ yg) {
  __shared__ unsigned short dxl[2][SCAN_T][2][16];  // [buf][t][{d,x}][e] bf16
  __shared__ float gl[2][SCAN_T][16];
  __shared__ float BCl[2][SCAN_T][32];              // [t][0:16)=B, [16:32)=C
  __shared__ float yl[SCAN_T][16];
  int tid = threadIdx.x;
  int n = tid & 15, el = tid >> 4;
  int w = tid >> 6, lane = tid & 63;
  int e0 = blockIdx.x * 16;
  int b = blockIdx.y;
  int e = e0 + el;
  float A2 = -__expf(A_log[e * 16 + n]) * 1.44269504f;   // pre-scale by log2(e)
  float wd = W_D[e];
  float h = 0.f;

  const unsigned short* gdl = delta_bf + (size_t)b * NL * NE + e0;
  const unsigned short* gx  = x_bf + (size_t)b * NL * NE + e0;
  const float* gg  = gcat + (size_t)b * NL * 8192 + e0;
  const float* gBC = bc + (size_t)b * NL * 32;

  // dx combined stage: lane l -> t=w*16+(l>>2); (l>>1)&1 selects x vs d; (l&1) selects 8-elem half
  const unsigned short* dxsrc = ((lane >> 1) & 1) ? gx : gdl;
  int dxrow = w * 16 + (lane >> 2);
  int dxcol = (lane & 1) * 8;
  int grow = w * 16 + (lane >> 2);
  int gcol = (lane & 3) * 4;
  int bcrow = lane >> 3;
  int bccol = (lane & 7) * 4;

  auto stage = [&](int buf, int c) {
    int l0 = c * SCAN_T;
    load_lds16(dxsrc + (size_t)(l0 + dxrow) * NE + dxcol, &dxl[buf][w * 16][0][0]);
    load_lds16(gg + (size_t)(l0 + grow) * 8192 + gcol, &gl[buf][w * 16][0]);
    load_lds16(gBC + (size_t)(l0 + w * 16 + bcrow) * 32 + bccol, &BCl[buf][w * 16][0]);
    load_lds16(gBC + (size_t)(l0 + w * 16 + 8 + bcrow) * 32 + bccol, &BCl[buf][w * 16 + 8][0]);
  };

  stage(0, 0);
  const int nch = NL / SCAN_T;  // 16
  for (int c = 0; c < nch; ++c) {
    int cur = c & 1;
    if (c + 1 < nch) {
      stage(cur ^ 1, c + 1);
      asm volatile("s_waitcnt vmcnt(4)" ::: "memory");  // chunk c landed; c+1 in flight
    } else {
      asm volatile("s_waitcnt vmcnt(0)" ::: "memory");
    }
    __syncthreads();
    int l0 = c * SCAN_T;
#pragma unroll 8
    for (int t = 0; t < SCAN_T; ++t) {
      float dc = bf2f(dxl[cur][t][0][el]);
      float xc = bf2f(dxl[cur][t][1][el]);
      float Bc = BCl[cur][t][n];
      float Cc = BCl[cur][t][16 + n];
      float a = dc * A2, ed;
      asm("v_exp_f32 %0, %1" : "=v"(ed) : "v"(a));     // exp2(dc*A*log2e)
      h = ed * h + (dc * xc) * Bc;
      float p = h * Cc;
      // 16-lane sum via DPP tree
      p += dpp_mov<0xB1>(p);    // quad_perm xor1
      p += dpp_mov<0x4E>(p);    // quad_perm xor2
      p += dpp_mov<0x141>(p);   // row_half_mirror
      p += dpp_mov<0x140>(p);   // row_mirror
      if (n == 0) yl[t][el] = p + xc * wd;
    }
    __syncthreads();
    // write phase: y * g (g already silu'd), coalesced bf16 store
    {
      int t = tid >> 2, part = tid & 3;
      f32x4 yv = *(const f32x4*)&yl[t][part * 4];
      f32x4 gv = *(const f32x4*)&gl[cur][t][part * 4];
      ushort4_t o;
#pragma unroll
      for (int j = 0; j < 4; ++j) o[j] = f2bf(yv[j] * gv[j]);
      *(ushort4_t*)(yg + (size_t)(b * NL + l0 + t) * NE + e0 + part * 4) = o;
    }
    __syncthreads();
  }
}

// ---------------- host launcher ----------------
extern "C" void kernel_launch(void* const* d_in, const int* in_sizes, int n_in,
                              void* d_out, int out_size, void* d_ws, size_t ws_size,
                              hipStream_t stream) {
  const float* resid  = (const float*)d_in[0];
  const float* norm_w = (const float*)d_in[1];
  const float* skip_w = (const float*)d_in[2];
  const float* in_w   = (const float*)d_in[3];
  const float* conv_w = (const float*)d_in[4];
  const float* conv_b = (const float*)d_in[5];
  const float* wd1    = (const float*)d_in[6];
  const float* wd2    = (const float*)d_in[7];
  const float* wd2_b  = (const float*)d_in[8];
  const float* wB     = (const float*)d_in[9];
  const float* wC     = (const float*)d_in[10];
  const float* A_log  = (const float*)d_in[11];
  const float* W_D    = (const float*)d_in[12];
  const float* out_w  = (const float*)d_in[13];
  float* out = (float*)d_out;

  char* ws = (char*)d_ws;
  size_t off = 0;
  auto alloc = [&](size_t bytes) -> void* {
    void* p = ws + off;
    off += (bytes + 255) & ~(size_t)255;
    return p;
  };
  unsigned short* rn_bf      = (unsigned short*)alloc((size_t)NBL * ND * 2);
  unsigned short* wskipin_bf = (unsigned short*)alloc((size_t)2 * NE * ND * 2);  // [skip_w; in_w]
  unsigned short* wout_bf    = (unsigned short*)alloc((size_t)ND * NE * 2);
  unsigned short* wd2_bf     = (unsigned short*)alloc((size_t)NE * NR * 2);
  unsigned short* wcat_bf    = (unsigned short*)alloc((size_t)256 * NE * 2);
  float* cat_f               = (float*)alloc((size_t)NBL * 8192 * 4);  // [g | xin]
  unsigned short* x_bf       = (unsigned short*)alloc((size_t)NBL * NE * 2);
  float* part_f              = (float*)alloc((size_t)8 * NBL * 256 * 4);
  unsigned short* t_bf       = (unsigned short*)alloc((size_t)NBL * NR * 2);
  float* bc_f                = (float*)alloc((size_t)NBL * 32 * 4);
  unsigned short* yg_bf      = (unsigned short*)alloc((size_t)NBL * NE * 2);
  // delta (bf16) aliases wskipin_bf: wskipin consumed by fused GEMM (step 3),
  // delta written at step 8 -> stream-ordered, safe, deterministic.
  unsigned short* delta_bf = wskipin_bf;
  (void)ws_size; (void)in_sizes; (void)n_in; (void)out_size;

  // 1. RMSNorm -> rn bf16
  rmsnorm_kernel<<<dim3(NBL), dim3(256), 0, stream>>>(resid, norm_w, rn_bf);

  // 2. weight casts
  cast_bf16_kernel<<<dim3((NE * ND / 8 + 255) / 256), dim3(256), 0, stream>>>(skip_w, wskipin_bf, NE * ND / 8);
  cast_bf16_kernel<<<dim3((NE * ND / 8 + 255) / 256), dim3(256), 0, stream>>>(in_w, wskipin_bf + (size_t)NE * ND, NE * ND / 8);
  cast_bf16_kernel<<<dim3((ND * NE / 8 + 255) / 256), dim3(256), 0, stream>>>(out_w, wout_bf, ND * NE / 8);
  cast_bf16_kernel<<<dim3((NE * NR / 8 + 255) / 256), dim3(256), 0, stream>>>(wd2, wd2_bf, NE * NR / 8);
  build_wcat_kernel<<<dim3(256 * NE / 8 / 256), dim3(256), 0, stream>>>(wd1, wB, wC, wcat_bf);

  // 3. fused cat = rn @ [skip_w; in_w]^T   [2048,8192] k=2048; silu on skip half
  gemm_bt<3><<<dim3(8192 / 128, NBL / 128, 1), dim3(256), 0, stream>>>(
      rn_bf, wskipin_bf, cat_f, NBL, 8192, ND, ND / 32, nullptr, nullptr);

  // 5. conv + silu -> x_bf
  conv_silu_kernel<<<dim3((int)(((size_t)NB * NL * NE) / 256)), dim3(256), 0, stream>>>(
      cat_f, conv_w, conv_b, x_bf);

  // 6. tcat = x @ [wd1;wB;wC]^T  split-K=8 -> partials
  gemm_bt<0><<<dim3(256 / 128, NBL / 128, 8), dim3(256), 0, stream>>>(
      x_bf, wcat_bf, part_f, NBL, 256, NE, (NE / 32) / 8, nullptr, nullptr);
  // 7. reduce partials -> t_bf, bc (interleaved B|C)
  reduce_tcat_kernel<<<dim3((NBL * 160 + 255) / 256), dim3(256), 0, stream>>>(
      part_f, t_bf, bc_f);

  // 8. delta = softplus(t @ wd2^T + wd2_b) -> bf16  [2048,4096] k=128
  gemm_bt<1><<<dim3(NE / 128, NBL / 128, 1), dim3(256), 0, stream>>>(
      t_bf, wd2_bf, (float*)delta_bf, NBL, NE, NR, NR / 32, wd2_b, nullptr);

  // 9. selective scan + D-skip + gating -> yg bf16
  scan_kernel<<<dim3(NE / 16, NB), dim3(256), 0, stream>>>(
      delta_bf, x_bf, bc_f, cat_f, A_log, W_D, yg_bf);

  // 10. out = resid + yg @ out_w^T   [2048,2048] k=4096
  gemm_bt<2><<<dim3(ND / 128, NBL / 128, 1), dim3(256), 0, stream>>>(
      yg_bf, wout_bf, out, NBL, ND, NE, NE / 32, nullptr, resid);
}

// Round 6
// 426.841 us; speedup vs baseline: 1.7203x; 1.0733x over previous
//
#include <hip/hip_runtime.h>
#include <stdint.h>

// ---- problem constants ----
#define NB 2
#define NL 1024
#define ND 2048
#define NE 4096
#define NN 16
#define NR 128
#define NKC 4
#define NBL (NB*NL)          // 2048 rows
#define EPSV 1e-5f

typedef __attribute__((ext_vector_type(4))) float f32x4;
typedef __attribute__((ext_vector_type(8))) short short8;
typedef __attribute__((ext_vector_type(8))) unsigned short ushort8;
typedef __attribute__((ext_vector_type(4))) unsigned short ushort4_t;

__device__ __forceinline__ unsigned short f2bf(float f) {
  union { float f; unsigned u; } v; v.f = f;
  unsigned r = v.u + 0x7FFFu + ((v.u >> 16) & 1u);   // RNE
  return (unsigned short)(r >> 16);
}

__device__ __forceinline__ float bf2f(unsigned short u) {
  union { unsigned u; float f; } v; v.u = (unsigned)u << 16; return v.f;
}

__device__ __forceinline__ void load_lds16(const void* g, void* l) {
  __builtin_amdgcn_global_load_lds((const __attribute__((address_space(1))) void*)g,
                                   (__attribute__((address_space(3))) void*)l,
                                   16, 0, 0);
}

template<int CTRL>
__device__ __forceinline__ float dpp_mov(float v) {
  return __int_as_float(__builtin_amdgcn_update_dpp(
      0, __float_as_int(v), CTRL, 0xF, 0xF, true));
}

// ---------------- RMSNorm: resid[row,0:2048] -> rn_bf16 ----------------
__global__ void rmsnorm_kernel(const float* __restrict__ resid,
                               const float* __restrict__ nw,
                               unsigned short* __restrict__ rn) {
  int row = blockIdx.x;
  int tid = threadIdx.x;                 // 256 threads, 8 f32 each
  const float* r = resid + (size_t)row * ND;
  f32x4 v0 = *(const f32x4*)(r + tid * 8);
  f32x4 v1 = *(const f32x4*)(r + tid * 8 + 4);
  float vals[8];
#pragma unroll
  for (int i = 0; i < 4; ++i) { vals[i] = v0[i]; vals[4 + i] = v1[i]; }
  float ss = 0.f;
#pragma unroll
  for (int i = 0; i < 8; ++i) ss += vals[i] * vals[i];
  for (int o = 32; o > 0; o >>= 1) ss += __shfl_down(ss, o);
  __shared__ float ps[4];
  if ((tid & 63) == 0) ps[tid >> 6] = ss;
  __syncthreads();
  float tot = ps[0] + ps[1] + ps[2] + ps[3];
  float scale = rsqrtf(tot / (float)ND + EPSV);
  ushort8 o8;
#pragma unroll
  for (int i = 0; i < 8; ++i) o8[i] = f2bf(vals[i] * scale * nw[tid * 8 + i]);
  *(ushort8*)(rn + (size_t)row * ND + tid * 8) = o8;
}

// ---------------- generic f32 -> bf16 cast (8 elems/thread) ----------------
__global__ void cast_bf16_kernel(const float* __restrict__ in,
                                 unsigned short* __restrict__ out, int n8) {
  int i = blockIdx.x * blockDim.x + threadIdx.x;
  if (i >= n8) return;
  f32x4 a = *(const f32x4*)(in + (size_t)i * 8);
  f32x4 b = *(const f32x4*)(in + (size_t)i * 8 + 4);
  ushort8 o;
#pragma unroll
  for (int j = 0; j < 4; ++j) { o[j] = f2bf(a[j]); o[4 + j] = f2bf(b[j]); }
  *(ushort8*)(out + (size_t)i * 8) = o;
}

// ---- build concatenated [256 x 4096] bf16 weight: rows 0-127 wd1, 128-143 wB, 144-159 wC, rest 0
__global__ void build_wcat_kernel(const float* __restrict__ wd1,
                                  const float* __restrict__ wB,
                                  const float* __restrict__ wC,
                                  unsigned short* __restrict__ out) {
  int i = blockIdx.x * blockDim.x + threadIdx.x;   // total 256*4096/8 = 131072
  if (i >= 256 * NE / 8) return;
  int col8 = i & (NE / 8 - 1);
  int row = i >> 9;
  const float* src = nullptr; int srow = 0;
  if (row < 128)      { src = wd1; srow = row; }
  else if (row < 144) { src = wB;  srow = row - 128; }
  else if (row < 160) { src = wC;  srow = row - 144; }
  ushort8 o;
  if (src) {
    f32x4 a = *(const f32x4*)(src + (size_t)srow * NE + col8 * 8);
    f32x4 b = *(const f32x4*)(src + (size_t)srow * NE + col8 * 8 + 4);
#pragma unroll
    for (int j = 0; j < 4; ++j) { o[j] = f2bf(a[j]); o[4 + j] = f2bf(b[j]); }
  } else {
#pragma unroll
    for (int j = 0; j < 8; ++j) o[j] = 0;
  }
  *(ushort8*)(out + (size_t)row * NE + col8 * 8) = o;
}

// ======== 256x256 multi-phase counted-vmcnt GEMM (fused skip+in proj) ========
// C[M=2048, N=8192] = A[2048,2048] @ B[8192,2048]^T, bf16 MFMA.
// 8 waves (2M x 4N), per-wave 128x64 out. LDS: 4-slot ring of K-halves (K=32):
// A,B slots [256][32] bf16 (64B rows -> frag reads tile bank lines, no swizzle,
// linear global_load_lds). Stage K-half h+3 during h; counted vmcnt(8) at each
// K-half boundary (never 0 mid-loop); raw s_barrier (no vmcnt drain); setprio
// around MFMA clusters (T3+T4+T5).
// Output split: cols<4096 -> Gout=silu(v) f32 ; cols>=4096 -> Xout=bf16(v).
__global__ __launch_bounds__(512, 2)
void gemm256_fused(const unsigned short* __restrict__ A,
                   const unsigned short* __restrict__ B,
                   float* __restrict__ Gout,
                   unsigned short* __restrict__ Xout) {
  const int K = 2048, NH = K / 32;   // 64 K-halves
  __shared__ unsigned short Asl[4][8192];   // [slot][r*32+c]  r<256, c<32
  __shared__ unsigned short Bsl[4][8192];
  int tid = threadIdx.x;
  int w = tid >> 6, lane = tid & 63;
  int wm = w >> 2, wn = w & 3;
  int lr = lane & 15, kg8 = (lane >> 4) * 8;
  int m0 = blockIdx.y * 256, n0 = blockIdx.x * 256;

  // staging: thread tid covers slot elem q*4096 + tid*8  (q=0,1)
  //   -> r = q*128 + tid/4, c = (tid&3)*8 ; LDS dest uniform base + lane*16B
  const unsigned short* ga = A + (size_t)(m0 + (tid >> 2)) * K + (tid & 3) * 8;
  const unsigned short* gb = B + (size_t)(n0 + (tid >> 2)) * K + (tid & 3) * 8;
  char* ldsA0 = (char*)&Asl[0][0] + w * 1024;
  char* ldsB0 = (char*)&Bsl[0][0] + w * 1024;

  auto stageA = [&](int h) {
    int slot = h & 3, k0 = h * 32;
    load_lds16(ga + k0, ldsA0 + slot * 16384);
    load_lds16(ga + k0 + (size_t)128 * K, ldsA0 + slot * 16384 + 8192);
  };
  auto stageB = [&](int h) {
    int slot = h & 3, k0 = h * 32;
    load_lds16(gb + k0, ldsB0 + slot * 16384);
    load_lds16(gb + k0 + (size_t)128 * K, ldsB0 + slot * 16384 + 8192);
  };

  f32x4 acc[8][4];
#pragma unroll
  for (int i = 0; i < 8; ++i)
#pragma unroll
    for (int j = 0; j < 4; ++j) acc[i][j] = (f32x4){0.f, 0.f, 0.f, 0.f};

  // prologue: K-halves 0,1,2 in flight; wait for 0 (12 issued, drain oldest 4)
  stageA(0); stageB(0); stageA(1); stageB(1); stageA(2); stageB(2);
  asm volatile("s_waitcnt vmcnt(8)" ::: "memory");
  __builtin_amdgcn_s_barrier();

  for (int h = 0; h < NH; ++h) {
    int slot = h & 3;
    const unsigned short* As_ = &Asl[slot][0];
    const unsigned short* Bs_ = &Bsl[slot][0];
    int arow = wm * 128 + lr;
    int brow = wn * 64 + lr;
    short8 a[8], b[4];
    // ---- phase 0: m-frags 0-3 x n-frags 0-3 ----
#pragma unroll
    for (int i = 0; i < 4; ++i)
      a[i] = *(const short8*)&As_[(arow + i * 16) * 32 + kg8];
#pragma unroll
    for (int j = 0; j < 4; ++j)
      b[j] = *(const short8*)&Bs_[(brow + j * 16) * 32 + kg8];
    if (h + 3 < NH) stageA(h + 3);
    __builtin_amdgcn_s_barrier();
    __builtin_amdgcn_s_setprio(1);
#pragma unroll
    for (int i = 0; i < 4; ++i)
#pragma unroll
      for (int j = 0; j < 4; ++j)
        acc[i][j] = __builtin_amdgcn_mfma_f32_16x16x32_bf16(a[i], b[j], acc[i][j], 0, 0, 0);
    __builtin_amdgcn_s_setprio(0);
    __builtin_amdgcn_s_barrier();
    // ---- phase 1: m-frags 4-7 x n-frags 0-3 (b reused in regs) ----
#pragma unroll
    for (int i = 0; i < 4; ++i)
      a[4 + i] = *(const short8*)&As_[(arow + (4 + i) * 16) * 32 + kg8];
    if (h + 3 < NH) stageB(h + 3);
    __builtin_amdgcn_s_barrier();
    __builtin_amdgcn_s_setprio(1);
#pragma unroll
    for (int i = 0; i < 4; ++i)
#pragma unroll
      for (int j = 0; j < 4; ++j)
        acc[4 + i][j] = __builtin_amdgcn_mfma_f32_16x16x32_bf16(a[4 + i], b[j], acc[4 + i][j], 0, 0, 0);
    __builtin_amdgcn_s_setprio(0);
    // K-half boundary: h+1 must have landed; h+2,h+3 stay in flight
    if (h < NH - 3)       { asm volatile("s_waitcnt vmcnt(8)" ::: "memory"); }
    else if (h == NH - 3) { asm volatile("s_waitcnt vmcnt(4)" ::: "memory"); }
    else if (h == NH - 2) { asm volatile("s_waitcnt vmcnt(0)" ::: "memory"); }
    __builtin_amdgcn_s_barrier();
  }

  // epilogue: C/D col=lane&15, row=(lane>>4)*4+reg (verified layout)
  int rbase = m0 + wm * 128 + (lane >> 4) * 4;
  int cbase = n0 + wn * 64 + (lane & 15);
  bool isg = (n0 < 4096);
#pragma unroll
  for (int mf = 0; mf < 8; ++mf) {
#pragma unroll
    for (int nf = 0; nf < 4; ++nf) {
      int col = cbase + nf * 16;
#pragma unroll
      for (int rr = 0; rr < 4; ++rr) {
        int row = rbase + mf * 16 + rr;
        float v = acc[mf][nf][rr];
        if (isg) Gout[(size_t)row * 4096 + col] = v / (1.f + __expf(-v));
        else     Xout[(size_t)row * 4096 + (col - 4096)] = f2bf(v);
      }
    }
  }
}

// ---------------- bf16 MFMA GEMM: C[M,N] = A[M,K] @ B[N,K]^T ----------------
// 128x128 tile, 256 threads (4 waves 2x2), BK=32 (m97 structure).
// MODE 0: plain f32 store (with split-K partials via blockIdx.z)
// MODE 1: softplus(acc + bias[n]) -> bf16 store
// MODE 2: acc + add[idx]  (residual)
template<int MODE>
__global__ __launch_bounds__(256)
void gemm_bt(const unsigned short* __restrict__ A,
             const unsigned short* __restrict__ B,
             float* __restrict__ C,
             int M, int N, int K, int ksteps_per_z,
             const float* __restrict__ bias,
             const float* __restrict__ add) {
  __shared__ unsigned short As[128 * 32];
  __shared__ unsigned short Bs[128 * 32];
  int tid = threadIdx.x;
  int w = tid >> 6, lane = tid & 63;
  int m0 = blockIdx.y * 128, n0 = blockIdx.x * 128;
  int kz0 = blockIdx.z * ksteps_per_z * 32;
  if (MODE == 0) C += (size_t)blockIdx.z * M * N;

  f32x4 zero = {0.f, 0.f, 0.f, 0.f};
  f32x4 acc[4][4];
#pragma unroll
  for (int i = 0; i < 4; ++i)
#pragma unroll
    for (int j = 0; j < 4; ++j) acc[i][j] = zero;

  int wm = w >> 1, wn = w & 1;
  int lr = lane & 15, kg = lane >> 4;

  int fe0 = (w)*512 + lane * 8;
  int fe1 = (4 + w) * 512 + lane * 8;
  int r0 = fe0 >> 5, c0 = fe0 & 31;
  int r1 = fe1 >> 5, c1 = fe1 & 31;
  const unsigned short* Ag0 = A + (size_t)(m0 + r0) * K + c0;
  const unsigned short* Ag1 = A + (size_t)(m0 + r1) * K + c1;
  const unsigned short* Bg0 = B + (size_t)(n0 + r0) * K + c0;
  const unsigned short* Bg1 = B + (size_t)(n0 + r1) * K + c1;
  unsigned short* Al0 = As + (w) * 512;
  unsigned short* Al1 = As + (4 + w) * 512;
  unsigned short* Bl0 = Bs + (w) * 512;
  unsigned short* Bl1 = Bs + (4 + w) * 512;

  for (int ks = 0; ks < ksteps_per_z; ++ks) {
    int kk = kz0 + ks * 32;
    __syncthreads();
    load_lds16(Ag0 + kk, Al0);
    load_lds16(Ag1 + kk, Al1);
    load_lds16(Bg0 + kk, Bl0);
    load_lds16(Bg1 + kk, Bl1);
    asm volatile("s_waitcnt vmcnt(0)" ::: "memory");
    __syncthreads();
    short8 a[4], b[4];
#pragma unroll
    for (int i = 0; i < 4; ++i)
      a[i] = *(const short8*)&As[(wm * 64 + i * 16 + lr) * 32 + kg * 8];
#pragma unroll
    for (int j = 0; j < 4; ++j)
      b[j] = *(const short8*)&Bs[(wn * 64 + j * 16 + lr) * 32 + kg * 8];
#pragma unroll
    for (int i = 0; i < 4; ++i)
#pragma unroll
      for (int j = 0; j < 4; ++j)
        acc[i][j] = __builtin_amdgcn_mfma_f32_16x16x32_bf16(a[i], b[j], acc[i][j], 0, 0, 0);
  }

#pragma unroll
  for (int i = 0; i < 4; ++i) {
#pragma unroll
    for (int j = 0; j < 4; ++j) {
      int rbase = m0 + wm * 64 + i * 16 + kg * 4;
      int col = n0 + wn * 64 + j * 16 + lr;
#pragma unroll
      for (int r = 0; r < 4; ++r) {
        float v = acc[i][j][r];
        size_t idx = (size_t)(rbase + r) * N + col;
        if (MODE == 0) {
          C[idx] = v;
        } else if (MODE == 1) {
          float t = v + bias[col];
          ((unsigned short*)C)[idx] = f2bf((t > 20.f) ? t : log1pf(__expf(t)));
        } else {
          C[idx] = v + add[idx];
        }
      }
    }
  }
}

// ---------------- depthwise causal conv (K=4) + SiLU -> bf16 ----------------
// xin is bf16 [NBL][4096]
__global__ void conv_silu_kernel(const unsigned short* __restrict__ xin,
                                 const float* __restrict__ cw,
                                 const float* __restrict__ cb,
                                 unsigned short* __restrict__ xbf) {
  size_t idx = (size_t)blockIdx.x * blockDim.x + threadIdx.x;
  if (idx >= (size_t)NB * NL * NE) return;
  int e = (int)(idx & (NE - 1));
  int r = (int)(idx >> 12);            // b*NL + l
  int l = r & (NL - 1);
  float acc = cb[e];
#pragma unroll
  for (int k = 0; k < NKC; ++k) {
    int ls = l - 3 + k;
    if (ls >= 0) acc += bf2f(xin[(size_t)(r - 3 + k) * NE + e]) * cw[e * 4 + k];
  }
  float s = acc / (1.f + __expf(-acc));
  xbf[idx] = f2bf(s);
}

// ---------------- reduce split-K partials of the concat GEMM ----------------
// part[8][NBL][256] -> t_bf[NBL][128], bc[NBL][32] (B in [0:16), C in [16:32))
__global__ void reduce_tcat_kernel(const float* __restrict__ part,
                                   unsigned short* __restrict__ tbf,
                                   float* __restrict__ bc) {
  int idx = blockIdx.x * blockDim.x + threadIdx.x;
  if (idx >= NBL * 160) return;
  int m = idx / 160, c = idx - m * 160;
  float s = 0.f;
#pragma unroll
  for (int z = 0; z < 8; ++z) s += part[(size_t)z * NBL * 256 + (size_t)m * 256 + c];
  if (c < 128) tbf[m * 128 + c] = f2bf(s);
  else if (c < 144) bc[m * 32 + (c - 128)] = s;
  else bc[m * 32 + 16 + (c - 144)] = s;
}

// ---------------- selective-scan + D-skip + gating (LDS chunked, DPP reduce) ----
// block = 256 threads = 16 e's (one b); lane n = state index (16 lanes per e).
// bf16 delta/x interleaved-staged; BC interleaved [m][32]; g pre-silu'd (f32, stride 4096).
#define SCAN_T 64
__global__ __launch_bounds__(256)
void scan_kernel(const unsigned short* __restrict__ delta_bf,
                 const unsigned short* __restrict__ x_bf,
                 const float* __restrict__ bc,
                 const float* __restrict__ gf,      // silu(skip) [NBL][4096] f32
                 const float* __restrict__ A_log,
                 const float* __restrict__ W_D,
                 unsigned short* __restrict__ yg) {
  __shared__ unsigned short dxl[2][SCAN_T][2][16];  // [buf][t][{d,x}][e] bf16
  __shared__ float gl[2][SCAN_T][16];
  __shared__ float BCl[2][SCAN_T][32];              // [t][0:16)=B, [16:32)=C
  __shared__ float yl[SCAN_T][16];
  int tid = threadIdx.x;
  int n = tid & 15, el = tid >> 4;
  int w = tid >> 6, lane = tid & 63;
  int e0 = blockIdx.x * 16;
  int b = blockIdx.y;
  int e = e0 + el;
  float A2 = -__expf(A_log[e * 16 + n]) * 1.44269504f;   // pre-scale by log2(e)
  float wd = W_D[e];
  float h = 0.f;

  const unsigned short* gdl = delta_bf + (size_t)b * NL * NE + e0;
  const unsigned short* gx  = x_bf + (size_t)b * NL * NE + e0;
  const float* gg  = gf + (size_t)b * NL * 4096 + e0;
  const float* gBC = bc + (size_t)b * NL * 32;

  const unsigned short* dxsrc = ((lane >> 1) & 1) ? gx : gdl;
  int dxrow = w * 16 + (lane >> 2);
  int dxcol = (lane & 1) * 8;
  int grow = w * 16 + (lane >> 2);
  int gcol = (lane & 3) * 4;
  int bcrow = lane >> 3;
  int bccol = (lane & 7) * 4;

  auto stage = [&](int buf, int c) {
    int l0 = c * SCAN_T;
    load_lds16(dxsrc + (size_t)(l0 + dxrow) * NE + dxcol, &dxl[buf][w * 16][0][0]);
    load_lds16(gg + (size_t)(l0 + grow) * 4096 + gcol, &gl[buf][w * 16][0]);
    load_lds16(gBC + (size_t)(l0 + w * 16 + bcrow) * 32 + bccol, &BCl[buf][w * 16][0]);
    load_lds16(gBC + (size_t)(l0 + w * 16 + 8 + bcrow) * 32 + bccol, &BCl[buf][w * 16 + 8][0]);
  };

  stage(0, 0);
  const int nch = NL / SCAN_T;  // 16
  for (int c = 0; c < nch; ++c) {
    int cur = c & 1;
    if (c + 1 < nch) {
      stage(cur ^ 1, c + 1);
      asm volatile("s_waitcnt vmcnt(4)" ::: "memory");  // chunk c landed; c+1 in flight
    } else {
      asm volatile("s_waitcnt vmcnt(0)" ::: "memory");
    }
    __syncthreads();
    int l0 = c * SCAN_T;
#pragma unroll 8
    for (int t = 0; t < SCAN_T; ++t) {
      float dc = bf2f(dxl[cur][t][0][el]);
      float xc = bf2f(dxl[cur][t][1][el]);
      float Bc = BCl[cur][t][n];
      float Cc = BCl[cur][t][16 + n];
      float a = dc * A2, ed;
      asm("v_exp_f32 %0, %1" : "=v"(ed) : "v"(a));     // exp2(dc*A*log2e)
      h = ed * h + (dc * xc) * Bc;
      float p = h * Cc;
      p += dpp_mov<0xB1>(p);    // quad_perm xor1
      p += dpp_mov<0x4E>(p);    // quad_perm xor2
      p += dpp_mov<0x141>(p);   // row_half_mirror
      p += dpp_mov<0x140>(p);   // row_mirror
      if (n == 0) yl[t][el] = p + xc * wd;
    }
    __syncthreads();
    {
      int t = tid >> 2, part = tid & 3;
      f32x4 yv = *(const f32x4*)&yl[t][part * 4];
      f32x4 gv = *(const f32x4*)&gl[cur][t][part * 4];
      ushort4_t o;
#pragma unroll
      for (int j = 0; j < 4; ++j) o[j] = f2bf(yv[j] * gv[j]);
      *(ushort4_t*)(yg + (size_t)(b * NL + l0 + t) * NE + e0 + part * 4) = o;
    }
    __syncthreads();
  }
}

// ---------------- host launcher ----------------
extern "C" void kernel_launch(void* const* d_in, const int* in_sizes, int n_in,
                              void* d_out, int out_size, void* d_ws, size_t ws_size,
                              hipStream_t stream) {
  const float* resid  = (const float*)d_in[0];
  const float* norm_w = (const float*)d_in[1];
  const float* skip_w = (const float*)d_in[2];
  const float* in_w   = (const float*)d_in[3];
  const float* conv_w = (const float*)d_in[4];
  const float* conv_b = (const float*)d_in[5];
  const float* wd1    = (const float*)d_in[6];
  const float* wd2    = (const float*)d_in[7];
  const float* wd2_b  = (const float*)d_in[8];
  const float* wB     = (const float*)d_in[9];
  const float* wC     = (const float*)d_in[10];
  const float* A_log  = (const float*)d_in[11];
  const float* W_D    = (const float*)d_in[12];
  const float* out_w  = (const float*)d_in[13];
  float* out = (float*)d_out;

  char* ws = (char*)d_ws;
  size_t off = 0;
  auto alloc = [&](size_t bytes) -> void* {
    void* p = ws + off;
    off += (bytes + 255) & ~(size_t)255;
    return p;
  };
  unsigned short* rn_bf      = (unsigned short*)alloc((size_t)NBL * ND * 2);
  unsigned short* wskipin_bf = (unsigned short*)alloc((size_t)2 * NE * ND * 2);  // [skip_w; in_w]
  unsigned short* wout_bf    = (unsigned short*)alloc((size_t)ND * NE * 2);
  unsigned short* wd2_bf     = (unsigned short*)alloc((size_t)NE * NR * 2);
  unsigned short* wcat_bf    = (unsigned short*)alloc((size_t)256 * NE * 2);
  float* g_f                 = (float*)alloc((size_t)NBL * NE * 4);   // silu(skip)
  unsigned short* xin_bf     = (unsigned short*)alloc((size_t)NBL * NE * 2);
  unsigned short* x_bf       = (unsigned short*)alloc((size_t)NBL * NE * 2);
  float* part_f              = (float*)alloc((size_t)8 * NBL * 256 * 4);
  unsigned short* t_bf       = (unsigned short*)alloc((size_t)NBL * NR * 2);
  float* bc_f                = (float*)alloc((size_t)NBL * 32 * 4);
  unsigned short* yg_bf      = (unsigned short*)alloc((size_t)NBL * NE * 2);
  // delta (bf16) aliases wskipin_bf: wskipin consumed by fused GEMM (step 3),
  // delta written at step 8 -> stream-ordered, safe, deterministic.
  unsigned short* delta_bf = wskipin_bf;
  (void)ws_size; (void)in_sizes; (void)n_in; (void)out_size;

  // 1. RMSNorm -> rn bf16
  rmsnorm_kernel<<<dim3(NBL), dim3(256), 0, stream>>>(resid, norm_w, rn_bf);

  // 2. weight casts
  cast_bf16_kernel<<<dim3((NE * ND / 8 + 255) / 256), dim3(256), 0, stream>>>(skip_w, wskipin_bf, NE * ND / 8);
  cast_bf16_kernel<<<dim3((NE * ND / 8 + 255) / 256), dim3(256), 0, stream>>>(in_w, wskipin_bf + (size_t)NE * ND, NE * ND / 8);
  cast_bf16_kernel<<<dim3((ND * NE / 8 + 255) / 256), dim3(256), 0, stream>>>(out_w, wout_bf, ND * NE / 8);
  cast_bf16_kernel<<<dim3((NE * NR / 8 + 255) / 256), dim3(256), 0, stream>>>(wd2, wd2_bf, NE * NR / 8);
  build_wcat_kernel<<<dim3(256 * NE / 8 / 256), dim3(256), 0, stream>>>(wd1, wB, wC, wcat_bf);

  // 3. fused [g|xin] = rn @ [skip_w; in_w]^T  (256^2 pipelined kernel)
  gemm256_fused<<<dim3(8192 / 256, NBL / 256), dim3(512), 0, stream>>>(
      rn_bf, wskipin_bf, g_f, xin_bf);

  // 5. conv + silu -> x_bf
  conv_silu_kernel<<<dim3((int)(((size_t)NB * NL * NE) / 256)), dim3(256), 0, stream>>>(
      xin_bf, conv_w, conv_b, x_bf);

  // 6. tcat = x @ [wd1;wB;wC]^T  split-K=8 -> partials
  gemm_bt<0><<<dim3(256 / 128, NBL / 128, 8), dim3(256), 0, stream>>>(
      x_bf, wcat_bf, part_f, NBL, 256, NE, (NE / 32) / 8, nullptr, nullptr);
  // 7. reduce partials -> t_bf, bc (interleaved B|C)
  reduce_tcat_kernel<<<dim3((NBL * 160 + 255) / 256), dim3(256), 0, stream>>>(
      part_f, t_bf, bc_f);

  // 8. delta = softplus(t @ wd2^T + wd2_b) -> bf16  [2048,4096] k=128
  gemm_bt<1><<<dim3(NE / 128, NBL / 128, 1), dim3(256), 0, stream>>>(
      t_bf, wd2_bf, (float*)delta_bf, NBL, NE, NR, NR / 32, wd2_b, nullptr);

  // 9. selective scan + D-skip + gating -> yg bf16
  scan_kernel<<<dim3(NE / 16, NB), dim3(256), 0, stream>>>(
      delta_bf, x_bf, bc_f, g_f, A_log, W_D, yg_bf);

  // 10. out = resid + yg @ out_w^T   [2048,2048] k=4096
  gemm_bt<2><<<dim3(ND / 128, NBL / 128, 1), dim3(256), 0, stream>>>(
      yg_bf, wout_bf, out, NBL, ND, NE, NE / 32, nullptr, resid);
}